// Round 12
// baseline (163.030 us; speedup 1.0000x reference)
//
#include <hip/hip_runtime.h>

// Chamfer min-matching loss, B=8, P=4096, D=2, fp32 — exact NN via x-sorted
// rank-window scan with certified exactness.
// Kernel 1 (xSort, 16 blocks): counting-sort each (batch,side) by x into 2048
//   x-bins (LDS histogram + shfl scan + scatter). Also zeroes out.
// Kernel 2 (winSearch, 256 blocks): stage sorted target (32KB) + u16 bin
//   starts (4KB) in LDS. Per query: rank = binstart[xbin(qx)], scan a FIXED
//   256-candidate window (128 x ds_read_b128, zero divergence), then certify:
//   unscanned-left x <= sp[lo].x + W (bin-sorted) => dx >= qx - sp[lo].x - W;
//   mirrored right. Expand by 64/side only if uncertified (P ~ 1e-5/query).
// R11 lesson: data-dependent ring loops are wave-hostile (tail-dominated,
// occupancy 7%); fixed-trip window scan is divergence-free.

#define NB    8
#define NP    4096
#define XBINS 2048
#define W     0.0048828125f      // 10 / 2048
#define XMIN  -5.0f
#define INVW  204.8f
#define BSSTR (XBINS + 4)        // u32 stride, 16B-aligned
#define WH    128                // half-window (256 candidates)

__device__ __forceinline__ int xbin(float x) {
    int i = (int)((x - XMIN) * INVW);
    return i < 0 ? 0 : (i > XBINS - 1 ? XBINS - 1 : i);
}

// ---- Kernel 1: counting sort by x-bin, one block per (batch, side) ----
__global__ __launch_bounds__(256) void xSort(const float* __restrict__ pred,
                                             const float* __restrict__ gt,
                                             float2* __restrict__ P,      // [16][NP]
                                             unsigned* __restrict__ BS,   // [16][BSSTR]
                                             float* __restrict__ out) {
    __shared__ unsigned cnt[XBINS];     // 8 KB
    __shared__ unsigned waveTot[4];

    int t = threadIdx.x;
    int s = blockIdx.x;                 // 0..15
    int b = s >> 1, side = s & 1;

    if (s == 0 && t == 0) *out = 0.0f;  // stream order: before winSearch atomics

    const float2* src = (const float2*)(side ? gt : pred) + (size_t)b * NP;
    float2*   dst = P  + (size_t)s * NP;
    unsigned* bs  = BS + (size_t)s * BSSTR;

#pragma unroll
    for (int i = 0; i < XBINS / 256; ++i) cnt[t * (XBINS / 256) + i] = 0;
    __syncthreads();

    for (int i = t; i < NP; i += 256)
        atomicAdd(&cnt[xbin(src[i].x)], 1u);
    __syncthreads();

    unsigned local = 0;
#pragma unroll
    for (int i = 0; i < XBINS / 256; ++i) local += cnt[t * (XBINS / 256) + i];

    unsigned inc = local;
#pragma unroll
    for (int o = 1; o < 64; o <<= 1) {
        unsigned n = __shfl_up(inc, o, 64);
        if ((t & 63) >= o) inc += n;
    }
    if ((t & 63) == 63) waveTot[t >> 6] = inc;
    __syncthreads();
    unsigned wbase = 0;
#pragma unroll
    for (int w = 0; w < 4; ++w) if (w < (t >> 6)) wbase += waveTot[w];
    unsigned run = wbase + inc - local;

#pragma unroll
    for (int i = 0; i < XBINS / 256; ++i) {
        unsigned c = cnt[t * (XBINS / 256) + i];
        cnt[t * (XBINS / 256) + i] = run;
        run += c;
    }
    __syncthreads();

    for (int i = t; i < XBINS; i += 256) bs[i] = cnt[i];
    if (t == 0) bs[XBINS] = NP;
    __syncthreads();

    for (int i = t; i < NP; i += 256) {
        float2 p = src[i];
        unsigned pos = atomicAdd(&cnt[xbin(p.x)], 1u);
        dst[pos] = p;
    }
}

// ---- Kernel 2: fixed-window scan + certified expansion ----
__global__ __launch_bounds__(256) void winSearch(const float* __restrict__ pred,
                                                 const float* __restrict__ gt,
                                                 const float2* __restrict__ P,
                                                 const unsigned* __restrict__ BS,
                                                 float* __restrict__ out) {
    __shared__ __align__(16) float2 sp[NP];             // 32 KB sorted target
    __shared__ __align__(16) unsigned short sbs[XBINS]; // 4 KB bin starts

    int t     = threadIdx.x;
    int bid   = blockIdx.x;        // 0..255
    int qs    = bid & 15;          // dir*8 + b
    int slice = bid >> 4;          // 0..15
    int b = qs & 7, dir = qs >> 3;

    int tgt = b * 2 + (1 - dir);   // sorted target side
    const float2*   tp = P  + (size_t)tgt * NP;
    const unsigned* bs = BS + (size_t)tgt * BSSTR;

    // stage sorted points (32 KB) + bin starts packed to u16 (4 KB)
    const float4* tp4 = (const float4*)tp;
    float4*       sp4w = (float4*)sp;
#pragma unroll
    for (int i = 0; i < 8; ++i) sp4w[t + i * 256] = tp4[t + i * 256];
    const uint4* bs4  = (const uint4*)bs;
    uint2*       sbs2 = (uint2*)sbs;
#pragma unroll
    for (int i = 0; i < 2; ++i) {
        uint4 v = bs4[t + i * 256];
        sbs2[t + i * 256] = make_uint2(v.x | (v.y << 16), v.z | (v.w << 16));
    }

    // query from global (coalesced), independent of LDS
    const float2* qarr = (const float2*)(dir ? gt : pred) + (size_t)b * NP;
    float2 q = qarr[slice * 256 + t];
    __syncthreads();

    float qx = q.x, qy = q.y;
    int r0 = (int)sbs[xbin(qx)];

    int w0 = r0 - WH;
    if (w0 < 0) w0 = 0;
    if (w0 > NP - 2 * WH) w0 = NP - 2 * WH;
    w0 &= ~1;                       // 16B-align the b128 stream

    float best = 3.402823466e+38f;
    const float4* spc = (const float4*)sp;
    int base = w0 >> 1;
#pragma unroll 8
    for (int k = 0; k < WH; ++k) {  // 128 x b128 = 256 candidates, fixed trip
        float4 v = spc[base + k];
        float dx0 = qx - v.x, dy0 = qy - v.y;
        float dx1 = qx - v.z, dy1 = qy - v.w;
        float d0 = fmaf(dx0, dx0, dy0 * dy0);
        float d1 = fmaf(dx1, dx1, dy1 * dy1);
        best = fminf(fminf(best, d0), d1);   // v_min3_f32
    }

    // certify; expand only if needed (P ~ 1e-5 per query)
    int lo = w0, hi = w0 + 2 * WH;
    for (;;) {
        float lbL = (lo > 0)  ? fmaxf(qx - sp[lo].x - W, 0.0f) : 3.0e38f;
        float lbR = (hi < NP) ? fmaxf(sp[hi - 1].x - W - qx, 0.0f) : 3.0e38f;
        bool eL = (lo > 0)  && lbL * lbL < best;
        bool eR = (hi < NP) && lbR * lbR < best;
        if (!eL && !eR) break;
        if (eL) {
            int nlo = lo - 64 < 0 ? 0 : lo - 64;
            for (int k = nlo; k < lo; ++k) {
                float2 pt = sp[k];
                float dx = qx - pt.x, dy = qy - pt.y;
                best = fminf(best, fmaf(dx, dx, dy * dy));
            }
            lo = nlo;
        }
        if (eR) {
            int nhi = hi + 64 > NP ? NP : hi + 64;
            for (int k = hi; k < nhi; ++k) {
                float2 pt = sp[k];
                float dx = qx - pt.x, dy = qy - pt.y;
                best = fminf(best, fmaf(dx, dx, dy * dy));
            }
            hi = nhi;
        }
    }

    float v = sqrtf(fmaxf(best, 1e-12f));

#pragma unroll
    for (int o = 32; o > 0; o >>= 1) v += __shfl_down(v, o, 64);

    __shared__ float wsum[4];
    if ((t & 63) == 0) wsum[t >> 6] = v;
    __syncthreads();
    if (t == 0)
        atomicAdd(out, ((wsum[0] + wsum[1]) + (wsum[2] + wsum[3])) *
                           (0.5f / (float)(NB * NP)));
}

extern "C" void kernel_launch(void* const* d_in, const int* in_sizes, int n_in,
                              void* d_out, int out_size, void* d_ws, size_t ws_size,
                              hipStream_t stream) {
    const float* pred = (const float*)d_in[0];
    const float* gt   = (const float*)d_in[1];
    float*       out  = (float*)d_out;

    float2*   P  = (float2*)d_ws;                       // 16 * 4096 * 8 B = 512 KB
    unsigned* BS = (unsigned*)(P + (size_t)16 * NP);    // 16 * 2052 * 4 B

    (void)in_sizes; (void)n_in; (void)out_size; (void)ws_size;

    xSort<<<16, 256, 0, stream>>>(pred, gt, P, BS, out);
    winSearch<<<256, 256, 0, stream>>>(pred, gt, P, BS, out);
}

// Round 13
// 116.822 us; speedup vs baseline: 1.3955x; 1.3955x over previous
//
#include <hip/hip_runtime.h>

// Chamfer min-matching loss, B=8, P=4096, D=2, fp32 — exact NN via x-sorted
// rank-window scan with certified exactness.
// Kernel 1 (xSort, 16 blocks): counting-sort each (batch,side) by x into 2048
//   x-bins (LDS histogram + shfl scan + scatter). Also zeroes out.
// Kernel 2 (winSearch, 256 blocks): stage sorted target (32KB) + u16 bin
//   starts (4KB) in LDS. Queries read from the SORTED query-side array
//   (mean is order-invariant) -> adjacent lanes have adjacent ranks -> the
//   fixed 256-candidate window scan is a contiguous conflict-free LDS stream
//   and certification branches are wave-uniform.
//   Certify: unscanned-left x <= sp[lo].x + W (bin-sorted) => dx bound;
//   mirrored right. Expand only if uncertified (outlier-y queries, ~0.1%).
// R12 lesson: unsorted queries -> random per-lane window bases -> 1.1M LDS
// bank conflicts -> 160 us. Sorted queries fix the access structure.

#define NB    8
#define NP    4096
#define XBINS 2048
#define W     0.0048828125f      // 10 / 2048
#define XMIN  -5.0f
#define INVW  204.8f
#define BSSTR (XBINS + 4)        // u32 stride, 16B-aligned
#define WH    128                // half-window (256 candidates)

__device__ __forceinline__ int xbin(float x) {
    int i = (int)((x - XMIN) * INVW);
    return i < 0 ? 0 : (i > XBINS - 1 ? XBINS - 1 : i);
}

// ---- Kernel 1: counting sort by x-bin, one block per (batch, side) ----
__global__ __launch_bounds__(256) void xSort(const float* __restrict__ pred,
                                             const float* __restrict__ gt,
                                             float2* __restrict__ P,      // [16][NP]
                                             unsigned* __restrict__ BS,   // [16][BSSTR]
                                             float* __restrict__ out) {
    __shared__ unsigned cnt[XBINS];     // 8 KB
    __shared__ unsigned waveTot[4];

    int t = threadIdx.x;
    int s = blockIdx.x;                 // 0..15
    int b = s >> 1, side = s & 1;

    if (s == 0 && t == 0) *out = 0.0f;  // stream order: before winSearch atomics

    const float2* src = (const float2*)(side ? gt : pred) + (size_t)b * NP;
    float2*   dst = P  + (size_t)s * NP;
    unsigned* bs  = BS + (size_t)s * BSSTR;

#pragma unroll
    for (int i = 0; i < XBINS / 256; ++i) cnt[t * (XBINS / 256) + i] = 0;
    __syncthreads();

    for (int i = t; i < NP; i += 256)
        atomicAdd(&cnt[xbin(src[i].x)], 1u);
    __syncthreads();

    unsigned local = 0;
#pragma unroll
    for (int i = 0; i < XBINS / 256; ++i) local += cnt[t * (XBINS / 256) + i];

    unsigned inc = local;
#pragma unroll
    for (int o = 1; o < 64; o <<= 1) {
        unsigned n = __shfl_up(inc, o, 64);
        if ((t & 63) >= o) inc += n;
    }
    if ((t & 63) == 63) waveTot[t >> 6] = inc;
    __syncthreads();
    unsigned wbase = 0;
#pragma unroll
    for (int w = 0; w < 4; ++w) if (w < (t >> 6)) wbase += waveTot[w];
    unsigned run = wbase + inc - local;

#pragma unroll
    for (int i = 0; i < XBINS / 256; ++i) {
        unsigned c = cnt[t * (XBINS / 256) + i];
        cnt[t * (XBINS / 256) + i] = run;
        run += c;
    }
    __syncthreads();

    for (int i = t; i < XBINS; i += 256) bs[i] = cnt[i];
    if (t == 0) bs[XBINS] = NP;
    __syncthreads();

    for (int i = t; i < NP; i += 256) {
        float2 p = src[i];
        unsigned pos = atomicAdd(&cnt[xbin(p.x)], 1u);
        dst[pos] = p;
    }
}

// ---- Kernel 2: fixed-window scan + certified expansion ----
__global__ __launch_bounds__(256) void winSearch(const float2* __restrict__ P,
                                                 const unsigned* __restrict__ BS,
                                                 float* __restrict__ out) {
    __shared__ __align__(16) float2 sp[NP];             // 32 KB sorted target
    __shared__ __align__(16) unsigned short sbs[XBINS]; // 4 KB bin starts

    int t     = threadIdx.x;
    int bid   = blockIdx.x;        // 0..255
    int qs    = bid & 15;          // dir*8 + b
    int slice = bid >> 4;          // 0..15
    int b = qs & 7, dir = qs >> 3;

    int tgt = b * 2 + (1 - dir);   // sorted target side
    const float2*   tp = P  + (size_t)tgt * NP;
    const unsigned* bs = BS + (size_t)tgt * BSSTR;

    // stage sorted points (32 KB) + bin starts packed to u16 (4 KB)
    const float4* tp4 = (const float4*)tp;
    float4*       sp4w = (float4*)sp;
#pragma unroll
    for (int i = 0; i < 8; ++i) sp4w[t + i * 256] = tp4[t + i * 256];
    const uint4* bs4  = (const uint4*)bs;
    uint2*       sbs2 = (uint2*)sbs;
#pragma unroll
    for (int i = 0; i < 2; ++i) {
        uint4 v = bs4[t + i * 256];
        sbs2[t + i * 256] = make_uint2(v.x | (v.y << 16), v.z | (v.w << 16));
    }

    // query from the SORTED query-side array (coalesced; order-invariant mean)
    const float2* qarr = P + (size_t)(b * 2 + dir) * NP;
    float2 q = qarr[slice * 256 + t];
    __syncthreads();

    float qx = q.x, qy = q.y;
    int r0 = (int)sbs[xbin(qx)];

    int w0 = r0 - WH;
    if (w0 < 0) w0 = 0;
    if (w0 > NP - 2 * WH) w0 = NP - 2 * WH;
    w0 &= ~1;                       // 16B-align the b128 stream

    float best = 3.402823466e+38f;
    const float4* spc = (const float4*)sp;
    int base = w0 >> 1;
#pragma unroll 8
    for (int k = 0; k < WH; ++k) {  // 128 x b128 = 256 candidates, fixed trip
        float4 v = spc[base + k];
        float dx0 = qx - v.x, dy0 = qy - v.y;
        float dx1 = qx - v.z, dy1 = qy - v.w;
        float d0 = fmaf(dx0, dx0, dy0 * dy0);
        float d1 = fmaf(dx1, dx1, dy1 * dy1);
        best = fminf(fminf(best, d0), d1);   // v_min3_f32
    }

    // certify; expand only if needed (rare, outlier-y queries)
    int lo = w0, hi = w0 + 2 * WH;
    for (;;) {
        float lbL = (lo > 0)  ? fmaxf(qx - sp[lo].x - W, 0.0f) : 3.0e38f;
        float lbR = (hi < NP) ? fmaxf(sp[hi - 1].x - W - qx, 0.0f) : 3.0e38f;
        bool eL = (lo > 0)  && lbL * lbL < best;
        bool eR = (hi < NP) && lbR * lbR < best;
        if (!eL && !eR) break;
        if (eL) {
            int nlo = lo - 64 < 0 ? 0 : lo - 64;
            int a = nlo >> 1;
#pragma unroll 4
            for (int k = 0; k < 32; ++k) {          // 64 candidates via float4
                if (a + k < (lo >> 1)) {
                    float4 v = spc[a + k];
                    float dx0 = qx - v.x, dy0 = qy - v.y;
                    float dx1 = qx - v.z, dy1 = qy - v.w;
                    best = fminf(best, fmaf(dx0, dx0, dy0 * dy0));
                    best = fminf(best, fmaf(dx1, dx1, dy1 * dy1));
                }
            }
            lo = nlo;
        }
        if (eR) {
            int nhi = hi + 64 > NP ? NP : hi + 64;
            int a = hi >> 1;
#pragma unroll 4
            for (int k = 0; k < 32; ++k) {
                if (a + k < (nhi >> 1)) {
                    float4 v = spc[a + k];
                    float dx0 = qx - v.x, dy0 = qy - v.y;
                    float dx1 = qx - v.z, dy1 = qy - v.w;
                    best = fminf(best, fmaf(dx0, dx0, dy0 * dy0));
                    best = fminf(best, fmaf(dx1, dx1, dy1 * dy1));
                }
            }
            hi = nhi;
        }
    }

    float v = sqrtf(fmaxf(best, 1e-12f));

#pragma unroll
    for (int o = 32; o > 0; o >>= 1) v += __shfl_down(v, o, 64);

    __shared__ float wsum[4];
    if ((t & 63) == 0) wsum[t >> 6] = v;
    __syncthreads();
    if (t == 0)
        atomicAdd(out, ((wsum[0] + wsum[1]) + (wsum[2] + wsum[3])) *
                           (0.5f / (float)(NB * NP)));
}

extern "C" void kernel_launch(void* const* d_in, const int* in_sizes, int n_in,
                              void* d_out, int out_size, void* d_ws, size_t ws_size,
                              hipStream_t stream) {
    const float* pred = (const float*)d_in[0];
    const float* gt   = (const float*)d_in[1];
    float*       out  = (float*)d_out;

    float2*   P  = (float2*)d_ws;                       // 16 * 4096 * 8 B = 512 KB
    unsigned* BS = (unsigned*)(P + (size_t)16 * NP);    // 16 * 2052 * 4 B

    (void)in_sizes; (void)n_in; (void)out_size; (void)ws_size;

    xSort<<<16, 256, 0, stream>>>(pred, gt, P, BS, out);
    winSearch<<<256, 256, 0, stream>>>(P, BS, out);
}

// Round 14
// 25.875 us; speedup vs baseline: 6.3007x; 4.5149x over previous
//
#include <hip/hip_runtime.h>

// Chamfer min-matching loss, B=8, P=4096, D=2, fp32 — exact NN via x-sorted
// rank-window scan + wave-cooperative rescue.
// Kernel 1 (xSort, 16 blocks): counting-sort each (batch,side) by x into 2048
//   x-bins (LDS histogram + shfl scan + scatter). Also zeroes out.
// Kernel 2 (winSearch, 256 blocks): stage sorted target (32KB) + u16 bin
//   starts (4KB) in LDS. Queries from the SORTED query-side array (order-
//   invariant mean) -> adjacent lanes adjacent ranks -> conflict-free window
//   scan. Fixed 256-candidate window, ONE certificate check, then ballot:
//   uncertified lanes (~1%) are rescued by a wave-cooperative full scan
//   (64 lanes x 32 float4 iters), shfl-min reduced. No per-lane expansion.
// R13 lesson: unbounded per-lane certify-expand loops straggler-serialize
// (occupancy 2%, 124 us); bounded cooperative rescue kills the tail.

#define NB    8
#define NP    4096
#define XBINS 2048
#define W     0.0048828125f      // 10 / 2048
#define XMIN  -5.0f
#define INVW  204.8f
#define BSSTR (XBINS + 4)        // u32 stride, 16B-aligned
#define WH    128                // half-window (256 candidates)

__device__ __forceinline__ int xbin(float x) {
    int i = (int)((x - XMIN) * INVW);
    return i < 0 ? 0 : (i > XBINS - 1 ? XBINS - 1 : i);
}

// ---- Kernel 1: counting sort by x-bin, one block per (batch, side) ----
__global__ __launch_bounds__(256) void xSort(const float* __restrict__ pred,
                                             const float* __restrict__ gt,
                                             float2* __restrict__ P,      // [16][NP]
                                             unsigned* __restrict__ BS,   // [16][BSSTR]
                                             float* __restrict__ out) {
    __shared__ unsigned cnt[XBINS];     // 8 KB
    __shared__ unsigned waveTot[4];

    int t = threadIdx.x;
    int s = blockIdx.x;                 // 0..15
    int b = s >> 1, side = s & 1;

    if (s == 0 && t == 0) *out = 0.0f;  // stream order: before winSearch atomics

    const float2* src = (const float2*)(side ? gt : pred) + (size_t)b * NP;
    float2*   dst = P  + (size_t)s * NP;
    unsigned* bs  = BS + (size_t)s * BSSTR;

#pragma unroll
    for (int i = 0; i < XBINS / 256; ++i) cnt[t * (XBINS / 256) + i] = 0;
    __syncthreads();

    for (int i = t; i < NP; i += 256)
        atomicAdd(&cnt[xbin(src[i].x)], 1u);
    __syncthreads();

    unsigned local = 0;
#pragma unroll
    for (int i = 0; i < XBINS / 256; ++i) local += cnt[t * (XBINS / 256) + i];

    unsigned inc = local;
#pragma unroll
    for (int o = 1; o < 64; o <<= 1) {
        unsigned n = __shfl_up(inc, o, 64);
        if ((t & 63) >= o) inc += n;
    }
    if ((t & 63) == 63) waveTot[t >> 6] = inc;
    __syncthreads();
    unsigned wbase = 0;
#pragma unroll
    for (int w = 0; w < 4; ++w) if (w < (t >> 6)) wbase += waveTot[w];
    unsigned run = wbase + inc - local;

#pragma unroll
    for (int i = 0; i < XBINS / 256; ++i) {
        unsigned c = cnt[t * (XBINS / 256) + i];
        cnt[t * (XBINS / 256) + i] = run;
        run += c;
    }
    __syncthreads();

    for (int i = t; i < XBINS; i += 256) bs[i] = cnt[i];
    if (t == 0) bs[XBINS] = NP;
    __syncthreads();

    for (int i = t; i < NP; i += 256) {
        float2 p = src[i];
        unsigned pos = atomicAdd(&cnt[xbin(p.x)], 1u);
        dst[pos] = p;
    }
}

// ---- Kernel 2: fixed-window scan + wave-cooperative rescue ----
__global__ __launch_bounds__(256) void winSearch(const float2* __restrict__ P,
                                                 const unsigned* __restrict__ BS,
                                                 float* __restrict__ out) {
    __shared__ __align__(16) float2 sp[NP];             // 32 KB sorted target
    __shared__ __align__(16) unsigned short sbs[XBINS]; // 4 KB bin starts

    int t     = threadIdx.x;
    int bid   = blockIdx.x;        // 0..255
    int qs    = bid & 15;          // dir*8 + b
    int slice = bid >> 4;          // 0..15
    int b = qs & 7, dir = qs >> 3;

    int tgt = b * 2 + (1 - dir);   // sorted target side
    const float2*   tp = P  + (size_t)tgt * NP;
    const unsigned* bs = BS + (size_t)tgt * BSSTR;

    // stage sorted points (32 KB) + bin starts packed to u16 (4 KB)
    const float4* tp4 = (const float4*)tp;
    float4*       sp4w = (float4*)sp;
#pragma unroll
    for (int i = 0; i < 8; ++i) sp4w[t + i * 256] = tp4[t + i * 256];
    const uint4* bs4  = (const uint4*)bs;
    uint2*       sbs2 = (uint2*)sbs;
#pragma unroll
    for (int i = 0; i < 2; ++i) {
        uint4 v = bs4[t + i * 256];
        sbs2[t + i * 256] = make_uint2(v.x | (v.y << 16), v.z | (v.w << 16));
    }

    // query from the SORTED query-side array (coalesced; order-invariant mean)
    const float2* qarr = P + (size_t)(b * 2 + dir) * NP;
    float2 q = qarr[slice * 256 + t];
    __syncthreads();

    float qx = q.x, qy = q.y;
    int r0 = (int)sbs[xbin(qx)];

    int w0 = r0 - WH;
    if (w0 < 0) w0 = 0;
    if (w0 > NP - 2 * WH) w0 = NP - 2 * WH;
    w0 &= ~1;                       // 16B-align the b128 stream

    float best = 3.402823466e+38f;
    const float4* spc = (const float4*)sp;
    int base = w0 >> 1;
#pragma unroll 8
    for (int k = 0; k < WH; ++k) {  // 128 x b128 = 256 candidates, fixed trip
        float4 v = spc[base + k];
        float dx0 = qx - v.x, dy0 = qy - v.y;
        float dx1 = qx - v.z, dy1 = qy - v.w;
        float d0 = fmaf(dx0, dx0, dy0 * dy0);
        float d1 = fmaf(dx1, dx1, dy1 * dy1);
        best = fminf(fminf(best, d0), d1);   // v_min3_f32
    }

    // ---- certificate (bin-sorted: k<w0 => p.x <= sp[w0].x + W, mirrored) ----
    float lbL = (w0 > 0)          ? fmaxf(qx - sp[w0].x - W, 0.0f)              : 3.0e38f;
    float lbR = (w0 + 2 * WH < NP) ? fmaxf(sp[w0 + 2 * WH - 1].x - W - qx, 0.0f) : 3.0e38f;
    bool uncert = (lbL * lbL < best) || (lbR * lbR < best);

    // ---- wave-cooperative rescue: full exact scan per uncertified lane ----
    unsigned long long mask = __ballot(uncert);
    int lane = t & 63;
    while (mask) {
        int l = __ffsll((long long)mask) - 1;
        mask &= mask - 1;
        float qlx = __shfl(qx, l, 64);
        float qly = __shfl(qy, l, 64);
        float rb = 3.402823466e+38f;
#pragma unroll 4
        for (int i = 0; i < 32; ++i) {      // 64 lanes x 32 x 2 pts = all 4096
            float4 v = spc[lane + i * 64];
            float dx0 = qlx - v.x, dy0 = qly - v.y;
            float dx1 = qlx - v.z, dy1 = qly - v.w;
            rb = fminf(rb, fmaf(dx0, dx0, dy0 * dy0));
            rb = fminf(rb, fmaf(dx1, dx1, dy1 * dy1));
        }
#pragma unroll
        for (int o = 32; o > 0; o >>= 1) rb = fminf(rb, __shfl_xor(rb, o, 64));
        if (lane == l) best = rb;           // exact full-scan result
    }

    float v = sqrtf(fmaxf(best, 1e-12f));

#pragma unroll
    for (int o = 32; o > 0; o >>= 1) v += __shfl_down(v, o, 64);

    __shared__ float wsum[4];
    if ((t & 63) == 0) wsum[t >> 6] = v;
    __syncthreads();
    if (t == 0)
        atomicAdd(out, ((wsum[0] + wsum[1]) + (wsum[2] + wsum[3])) *
                           (0.5f / (float)(NB * NP)));
}

extern "C" void kernel_launch(void* const* d_in, const int* in_sizes, int n_in,
                              void* d_out, int out_size, void* d_ws, size_t ws_size,
                              hipStream_t stream) {
    const float* pred = (const float*)d_in[0];
    const float* gt   = (const float*)d_in[1];
    float*       out  = (float*)d_out;

    float2*   P  = (float2*)d_ws;                       // 16 * 4096 * 8 B = 512 KB
    unsigned* BS = (unsigned*)(P + (size_t)16 * NP);    // 16 * 2052 * 4 B

    (void)in_sizes; (void)n_in; (void)out_size; (void)ws_size;

    xSort<<<16, 256, 0, stream>>>(pred, gt, P, BS, out);
    winSearch<<<256, 256, 0, stream>>>(P, BS, out);
}